// Round 7
// baseline (727.219 us; speedup 1.0000x reference)
//
#include <hip/hip_runtime.h>

// EmbeddingLSQ: out[t,d] = (idx[t]==0) ? 0 : rint(clamp(W[d,idx[t]]/a,-8,7))*a
// idx[t] = position of the 1.0 in one-hot row x[t,:].
//
// Single kernel. 4 tokens per 256-thr block, ONE INDEPENDENT WAVE PER TOKEN
// (no LDS, no __syncthreads) -> up to 32 waves/CU (2x the single-wave-block
// config, which caps at ~16 WG slots/CU). Scan uses 8 KB/wave windows
// (8 x uint4 per lane) with an integer OR nonzero check (one-hot: hit <=>
// nonzero bits; 1.0f = 0x3F800000), ballot early-exit once per window.
// Phase 2: 16 scattered w gathers/lane (L2/L3-absorbed; measured ~25-30 us)
// + fp32 LSQ fake-quant + coalesced 16B row stores.

typedef float        v4f __attribute__((ext_vector_type(4)));
typedef unsigned int v4u __attribute__((ext_vector_type(4)));
typedef unsigned int u32;

constexpr int VOCAB  = 32000;
constexpr int DIM    = 1024;
constexpr int TOKENS = 4096;
constexpr int V4     = VOCAB / 4;        // 8000 16B chunks per x row
constexpr int WPT    = 8;                // chunks/lane/window -> 8 KB window
constexpr int WIN    = 64 * WPT;         // 512 chunks
constexpr int NWIN   = V4 / WIN;         // 15 full windows
constexpr int TAILB  = NWIN * WIN;       // 7680
constexpr int TAILC  = (V4 - TAILB) / 64;// 5 tail chunks per lane

__device__ __forceinline__ int word_of(v4u c) {
    return c.x ? 0 : (c.y ? 1 : (c.z ? 2 : 3));
}

__global__ __launch_bounds__(256, 8) void emb_lsq_kernel(
    const float* __restrict__ x,
    const float* __restrict__ w,
    const float* __restrict__ alpha,
    float* __restrict__ out)
{
    const int lane = threadIdx.x & 63;
    const int t    = blockIdx.x * 4 + (threadIdx.x >> 6);  // token per wave

    // ---- Phase 1: find one-hot index (8 KB windows, OR-check, ballot) ----
    const v4u* xr = reinterpret_cast<const v4u*>(x + (size_t)t * VOCAB);
    int cand = -1;
    for (int k = 0; k < NWIN; ++k) {
        const int i = lane + WIN * k;
        v4u c0 = xr[i];            // 8 x 16B loads in flight (8 KB/wave)
        v4u c1 = xr[i +  64];
        v4u c2 = xr[i + 128];
        v4u c3 = xr[i + 192];
        v4u c4 = xr[i + 256];
        v4u c5 = xr[i + 320];
        v4u c6 = xr[i + 384];
        v4u c7 = xr[i + 448];
        u32 m0 = c0.x | c0.y | c0.z | c0.w;   // nonzero <=> contains the 1.0
        u32 m1 = c1.x | c1.y | c1.z | c1.w;
        u32 m2 = c2.x | c2.y | c2.z | c2.w;
        u32 m3 = c3.x | c3.y | c3.z | c3.w;
        u32 m4 = c4.x | c4.y | c4.z | c4.w;
        u32 m5 = c5.x | c5.y | c5.z | c5.w;
        u32 m6 = c6.x | c6.y | c6.z | c6.w;
        u32 m7 = c7.x | c7.y | c7.z | c7.w;
        if      (m0) cand = 4 * (i      ) + word_of(c0);   // one-hot: at most
        else if (m1) cand = 4 * (i +  64) + word_of(c1);   // one lane/chunk hits
        else if (m2) cand = 4 * (i + 128) + word_of(c2);
        else if (m3) cand = 4 * (i + 192) + word_of(c3);
        else if (m4) cand = 4 * (i + 256) + word_of(c4);
        else if (m5) cand = 4 * (i + 320) + word_of(c5);
        else if (m6) cand = 4 * (i + 384) + word_of(c6);
        else if (m7) cand = 4 * (i + 448) + word_of(c7);
        if (__ballot(cand >= 0)) break;       // one register-only check / 8 KB
    }
    if (!__ballot(cand >= 0)) {               // tail: chunks 7680..7999
        #pragma unroll
        for (int j = 0; j < TAILC; ++j) {
            const int c = TAILB + lane + 64 * j;
            v4u v = xr[c];
            u32 m = v.x | v.y | v.z | v.w;
            if (cand < 0 && m) cand = 4 * c + word_of(v);
        }
    }
    const unsigned long long msk = __ballot(cand >= 0);
    const int idx = msk ? __shfl(cand, (int)__ffsll(msk) - 1) : 0;

    // ---- Phase 2: gather w column + LSQ fake-quant + coalesced stores ----
    v4f* orow = reinterpret_cast<v4f*>(out + (size_t)t * DIM);
    if (idx <= 0) {                           // PAD_IDX -> zero row
        v4f z = 0.f;
        #pragma unroll
        for (int j = 0; j < 4; ++j) orow[lane + 64 * j] = z;
    } else {
        const float a = alpha[0];
        const size_t col = (size_t)idx;
        float wv[16];
        #pragma unroll
        for (int j = 0; j < 4; ++j) {         // 16 independent gathers in flight
            const int d0 = 4 * lane + 256 * j;
            wv[4*j+0] = w[(size_t)(d0 + 0) * VOCAB + col];
            wv[4*j+1] = w[(size_t)(d0 + 1) * VOCAB + col];
            wv[4*j+2] = w[(size_t)(d0 + 2) * VOCAB + col];
            wv[4*j+3] = w[(size_t)(d0 + 3) * VOCAB + col];
        }
        #pragma unroll
        for (int j = 0; j < 4; ++j) {
            v4f q;
            q.x = rintf(fminf(fmaxf(wv[4*j+0] / a, -8.f), 7.f)) * a;
            q.y = rintf(fminf(fmaxf(wv[4*j+1] / a, -8.f), 7.f)) * a;
            q.z = rintf(fminf(fmaxf(wv[4*j+2] / a, -8.f), 7.f)) * a;
            q.w = rintf(fminf(fmaxf(wv[4*j+3] / a, -8.f), 7.f)) * a;
            orow[lane + 64 * j] = q;          // 1 KB coalesced store/instr
        }
    }
}

extern "C" void kernel_launch(void* const* d_in, const int* in_sizes, int n_in,
                              void* d_out, int out_size, void* d_ws, size_t ws_size,
                              hipStream_t stream) {
    const float* x     = (const float*)d_in[0];   // [TOKENS, VOCAB]
    const float* w     = (const float*)d_in[1];   // [DIM, VOCAB]
    const float* alpha = (const float*)d_in[2];   // [1]
    float* out         = (float*)d_out;           // [TOKENS, DIM]

    emb_lsq_kernel<<<TOKENS / 4, 256, 0, stream>>>(x, w, alpha, out);
}